// Round 1
// baseline (503.528 us; speedup 1.0000x reference)
//
#include <hip/hip_runtime.h>

#define NN 50000
#define NE 800000
// IN_C=16, EDGE_IN=16, HID=32, HEADS=4, HC=128

// ---------------- Kernel 1: node linears -------------------------------
// one 64-lane wave per node: q[N,128], kv[N,256] (k then v), qe[N,64], skip[N,32]
__global__ __launch_bounds__(256) void node_linear_kernel(
    const float* __restrict__ x,
    const float* __restrict__ Wq, const float* __restrict__ bq,
    const float* __restrict__ Wk, const float* __restrict__ bk,
    const float* __restrict__ Wv, const float* __restrict__ bv,
    const float* __restrict__ We,
    const float* __restrict__ Wskip, const float* __restrict__ bskip,
    float* __restrict__ q, float* __restrict__ kv,
    float* __restrict__ qe, float* __restrict__ skip) {
  int wave = threadIdx.x >> 6;
  int lane = threadIdx.x & 63;
  int n = blockIdx.x * 4 + wave;
  if (n >= NN) return;
  __shared__ float qtile[4][128];

  float xr[16];
#pragma unroll
  for (int i = 0; i < 16; i++) xr[i] = x[n * 16 + i];

  int c0 = lane, c1 = lane + 64;
  float q0 = bq[c0], q1 = bq[c1];
  float k0 = bk[c0], k1 = bk[c1];
  float v0 = bv[c0], v1 = bv[c1];
#pragma unroll
  for (int i = 0; i < 16; i++) {
    q0 += xr[i] * Wq[i * 128 + c0]; q1 += xr[i] * Wq[i * 128 + c1];
    k0 += xr[i] * Wk[i * 128 + c0]; k1 += xr[i] * Wk[i * 128 + c1];
    v0 += xr[i] * Wv[i * 128 + c0]; v1 += xr[i] * Wv[i * 128 + c1];
  }
  q[n * 128 + c0] = q0; q[n * 128 + c1] = q1;
  kv[n * 256 + c0] = k0; kv[n * 256 + c1] = k1;
  kv[n * 256 + 128 + c0] = v0; kv[n * 256 + 128 + c1] = v1;
  qtile[wave][c0] = q0; qtile[wave][c1] = q1;

  if (lane < 32) {
    float sk = bskip[lane];
#pragma unroll
    for (int i = 0; i < 16; i++) sk += xr[i] * Wskip[i * 32 + lane];
    skip[n * 32 + lane] = sk;
  }

  // qe[h][i] = sum_c q[h*32+c] * We[i*128 + h*32 + c]   (lane: h=lane>>4, i=lane&15)
  int h = lane >> 4, ii = lane & 15;
  float acc = 0.f;
#pragma unroll
  for (int c = 0; c < 32; c++)
    acc += qtile[wave][h * 32 + c] * We[ii * 128 + h * 32 + c];
  qe[n * 64 + lane] = acc;
}

// ---------------- CSR build --------------------------------------------
__global__ __launch_bounds__(256) void count_kernel(const int* __restrict__ ei,
                                                    int* __restrict__ counts) {
  int e = blockIdx.x * 256 + threadIdx.x;
  if (e >= NE) return;
  atomicAdd(&counts[ei[NE + e]], 1);
}

__global__ __launch_bounds__(1024) void scan_kernel(const int* __restrict__ counts,
                                                    int* __restrict__ offs,
                                                    int* __restrict__ cursor) {
  __shared__ int sums[1024];
  int t = threadIdx.x;
  const int chunk = (NN + 1023) >> 10;
  int lo = t * chunk;
  int hi = lo + chunk; if (hi > NN) hi = NN;
  int sum = 0;
  for (int i = lo; i < hi; i++) sum += counts[i];
  sums[t] = sum;
  __syncthreads();
  for (int d = 1; d < 1024; d <<= 1) {
    int val = (t >= d) ? sums[t - d] : 0;
    __syncthreads();
    sums[t] += val;
    __syncthreads();
  }
  int run = (t == 0) ? 0 : sums[t - 1];
  for (int i = lo; i < hi; i++) {
    offs[i] = run; cursor[i] = run;
    run += counts[i];
  }
  if (t == 1023) offs[NN] = run;  // == NE
}

__global__ __launch_bounds__(256) void scatter_kernel(const int* __restrict__ ei,
                                                      int* __restrict__ cursor,
                                                      int* __restrict__ s_src,
                                                      int* __restrict__ s_eid) {
  int e = blockIdx.x * 256 + threadIdx.x;
  if (e >= NE) return;
  int dst = ei[NE + e];
  int pos = atomicAdd(&cursor[dst], 1);
  s_src[pos] = ei[e];
  s_eid[pos] = e;
}

// ---------------- Kernel 3: per-dst-node online-softmax aggregation ----
// one wave per node; 16 lanes per head (h=lane>>4, t=lane&15, each lane owns c=t and c=t+16)
__global__ __launch_bounds__(256) void aggregate_kernel(
    const float* __restrict__ q, const float* __restrict__ kv,
    const float* __restrict__ qe, const float* __restrict__ edge_attr,
    const float* __restrict__ We, const float* __restrict__ skip,
    const int* __restrict__ offs, const int* __restrict__ s_src,
    const int* __restrict__ s_eid, float* __restrict__ outn) {
  int wave = threadIdx.x >> 6, lane = threadIdx.x & 63;
  int n = blockIdx.x * 4 + wave;
  if (n >= NN) return;
  int h = lane >> 4, t = lane & 15;
  int base = h * 32 + t;

  float q0 = q[n * 128 + base], q1 = q[n * 128 + base + 16];
  float qet = qe[n * 64 + lane];
  int off = offs[n], end = offs[n + 1];

  float m = -INFINITY, s = 0.f, av0 = 0.f, av1 = 0.f, ae = 0.f;
  for (int j = off; j < end; j++) {
    int src = s_src[j], eid = s_eid[j];
    const float* kvp = kv + src * 256;
    float k0 = kvp[base], k1 = kvp[base + 16];
    float v0 = kvp[128 + base], v1 = kvp[128 + base + 16];
    float eat = edge_attr[eid * 16 + t];
    float p = q0 * k0 + q1 * k1 + qet * eat;
    p += __shfl_xor(p, 1); p += __shfl_xor(p, 2);
    p += __shfl_xor(p, 4); p += __shfl_xor(p, 8);
    float alpha = p * 0.17677669529663687f;  // 1/sqrt(32)
    float nm = fmaxf(m, alpha);
    float sc = __expf(m - nm);   // first iter: exp(-inf)=0
    float w = __expf(alpha - nm);
    s = s * sc + w;
    av0 = av0 * sc + w * v0;
    av1 = av1 * sc + w * v1;
    ae = ae * sc + w * eat;
    m = nm;
  }
  float inv = (end > off) ? 1.f / s : 0.f;
  float r0 = av0 * inv, r1 = av1 * inv;
  int gb = lane & 48;
#pragma unroll
  for (int i = 0; i < 16; i++) {
    float aei = __shfl(ae, gb | i) * inv;
    r0 += aei * We[i * 128 + base];
    r1 += aei * We[i * 128 + base + 16];
  }
  // mean over heads
  r0 += __shfl_xor(r0, 16); r0 += __shfl_xor(r0, 32);
  r1 += __shfl_xor(r1, 16); r1 += __shfl_xor(r1, 32);
  if (lane < 16) {
    outn[n * 32 + t] = 0.25f * r0 + skip[n * 32 + t];
    outn[n * 32 + t + 16] = 0.25f * r1 + skip[n * 32 + t + 16];
  }
}

// ---------------- Kernel 4: per-edge MLP -------------------------------
__global__ __launch_bounds__(256) void mlp_kernel(
    const int* __restrict__ ei, const float* __restrict__ edge_attr,
    const float* __restrict__ outn,
    const float* __restrict__ W1, const float* __restrict__ b1,
    const float* __restrict__ W2, const float* __restrict__ b2,
    float* __restrict__ out) {
  int e = blockIdx.x * 256 + threadIdx.x;
  if (e >= NE) return;
  int src = ei[e], dst = ei[NE + e];
  const float* os = outn + src * 32;
  const float* od = outn + dst * 32;
  const float* ea = edge_attr + e * 16;

  float hbuf[32];
#pragma unroll
  for (int j = 0; j < 32; j++) hbuf[j] = b1[j];
#pragma unroll
  for (int i = 0; i < 32; i++) {
    float f = os[i];
#pragma unroll
    for (int j = 0; j < 32; j++) hbuf[j] += f * W1[i * 32 + j];
  }
#pragma unroll
  for (int i = 0; i < 16; i++) {
    float f = ea[i];
#pragma unroll
    for (int j = 0; j < 32; j++) hbuf[j] += f * W1[(32 + i) * 32 + j];
  }
#pragma unroll
  for (int i = 0; i < 32; i++) {
    float f = od[i];
#pragma unroll
    for (int j = 0; j < 32; j++) hbuf[j] += f * W1[(48 + i) * 32 + j];
  }
  float acc = b2[0];
#pragma unroll
  for (int j = 0; j < 32; j++) acc += fmaxf(hbuf[j], 0.f) * W2[j];
  out[e] = acc;
}

// ---------------- launch -----------------------------------------------
extern "C" void kernel_launch(void* const* d_in, const int* in_sizes, int n_in,
                              void* d_out, int out_size, void* d_ws, size_t ws_size,
                              hipStream_t stream) {
  const float* x         = (const float*)d_in[0];
  const int*   ei        = (const int*)d_in[1];
  const float* edge_attr = (const float*)d_in[2];
  const float* Wq = (const float*)d_in[3],  *bq = (const float*)d_in[4];
  const float* Wk = (const float*)d_in[5],  *bk = (const float*)d_in[6];
  const float* Wv = (const float*)d_in[7],  *bv = (const float*)d_in[8];
  const float* We = (const float*)d_in[9];
  const float* Wskip = (const float*)d_in[10], *bskip = (const float*)d_in[11];
  const float* W1 = (const float*)d_in[12], *b1 = (const float*)d_in[13];
  const float* W2 = (const float*)d_in[14], *b2 = (const float*)d_in[15];
  float* out = (float*)d_out;

  // workspace layout
  float* q    = (float*)d_ws;            // N*128
  float* kv   = q    + (size_t)NN * 128; // N*256
  float* qe   = kv   + (size_t)NN * 256; // N*64
  float* skip = qe   + (size_t)NN * 64;  // N*32
  float* outn = skip + (size_t)NN * 32;  // N*32
  int* counts = (int*)(outn + (size_t)NN * 32); // N
  int* offs   = counts + NN;             // N+1
  int* cursor = offs + NN + 1;           // N
  int* s_src  = cursor + NN;             // E
  int* s_eid  = s_src + NE;              // E

  hipMemsetAsync(counts, 0, NN * sizeof(int), stream);

  node_linear_kernel<<<NN / 4, 256, 0, stream>>>(x, Wq, bq, Wk, bk, Wv, bv, We,
                                                 Wskip, bskip, q, kv, qe, skip);
  count_kernel<<<NE / 256, 256, 0, stream>>>(ei, counts);
  scan_kernel<<<1, 1024, 0, stream>>>(counts, offs, cursor);
  scatter_kernel<<<NE / 256, 256, 0, stream>>>(ei, cursor, s_src, s_eid);
  aggregate_kernel<<<NN / 4, 256, 0, stream>>>(q, kv, qe, edge_attr, We, skip,
                                               offs, s_src, s_eid, outn);
  mlp_kernel<<<NE / 256, 256, 0, stream>>>(ei, edge_attr, outn, W1, b1, W2, b2, out);
}

// Round 2
// 492.662 us; speedup vs baseline: 1.0221x; 1.0221x over previous
//
#include <hip/hip_runtime.h>
#include <hip/hip_fp16.h>

#define NN 50000
#define NE 800000
// IN_C=16, EDGE_IN=16, HID=32, HEADS=4, HC=128

// ---------------- Kernel 1: node linears -------------------------------
// one wave per node; lane = (h=lane>>4, t=lane&15), base = h*32+t
// outputs: qh[N,64] half2 (q_base,q_base+16), kvh[N,64] uint2 = half4(k,k16,v,v16),
//          qe[N,64] f32
__global__ __launch_bounds__(256) void node_linear_kernel(
    const float* __restrict__ x,
    const float* __restrict__ Wq, const float* __restrict__ bq,
    const float* __restrict__ Wk, const float* __restrict__ bk,
    const float* __restrict__ Wv, const float* __restrict__ bv,
    const float* __restrict__ We,
    __half2* __restrict__ qh, uint2* __restrict__ kvh,
    float* __restrict__ qe) {
  int wave = threadIdx.x >> 6;
  int lane = threadIdx.x & 63;
  int n = blockIdx.x * 4 + wave;
  if (n >= NN) return;
  int h = lane >> 4, t = lane & 15, base = h * 32 + t;

  float xr[16];
#pragma unroll
  for (int i = 0; i < 16; i++) xr[i] = x[n * 16 + i];

  float qb = bq[base], q16 = bq[base + 16];
  float kb = bk[base], k16 = bk[base + 16];
  float vb = bv[base], v16 = bv[base + 16];
#pragma unroll
  for (int i = 0; i < 16; i++) {
    qb  += xr[i] * Wq[i * 128 + base];
    q16 += xr[i] * Wq[i * 128 + base + 16];
    kb  += xr[i] * Wk[i * 128 + base];
    k16 += xr[i] * Wk[i * 128 + base + 16];
    vb  += xr[i] * Wv[i * 128 + base];
    v16 += xr[i] * Wv[i * 128 + base + 16];
  }
  qh[n * 64 + lane] = __floats2half2_rn(qb, q16);
  __half2 kk = __floats2half2_rn(kb, k16);
  __half2 vv = __floats2half2_rn(vb, v16);
  uint2 pk;
  pk.x = *(unsigned int*)&kk;
  pk.y = *(unsigned int*)&vv;
  kvh[n * 64 + lane] = pk;

  // qe[h][ii=t] = sum_{c=0..31} q[h*32+c] * We[ii*128 + h*32 + c]
  int gb = lane & 48;
  float acc = 0.f;
#pragma unroll
  for (int i = 0; i < 16; i++) {
    float qv  = __shfl(qb,  gb | i);
    float qv2 = __shfl(q16, gb | i);
    acc += qv * We[t * 128 + h * 32 + i] + qv2 * We[t * 128 + h * 32 + 16 + i];
  }
  qe[n * 64 + lane] = acc;
}

// ---------------- CSR build --------------------------------------------
__global__ __launch_bounds__(256) void count_kernel(const int* __restrict__ ei,
                                                    int* __restrict__ counts) {
  int e = blockIdx.x * 256 + threadIdx.x;
  if (e >= NE) return;
  atomicAdd(&counts[ei[NE + e]], 1);
}

__global__ __launch_bounds__(1024) void scan_kernel(const int* __restrict__ counts,
                                                    int* __restrict__ offs,
                                                    int* __restrict__ cursor) {
  __shared__ int sums[1024];
  int t = threadIdx.x;
  const int chunk = (NN + 1023) >> 10;
  int lo = t * chunk;
  int hi = lo + chunk; if (hi > NN) hi = NN;
  int sum = 0;
  for (int i = lo; i < hi; i++) sum += counts[i];
  sums[t] = sum;
  __syncthreads();
  for (int d = 1; d < 1024; d <<= 1) {
    int val = (t >= d) ? sums[t - d] : 0;
    __syncthreads();
    sums[t] += val;
    __syncthreads();
  }
  int run = (t == 0) ? 0 : sums[t - 1];
  for (int i = lo; i < hi; i++) {
    offs[i] = run; cursor[i] = run;
    run += counts[i];
  }
  if (t == 1023) offs[NN] = run;  // == NE
}

// scatter: build CSR (src,eid) pairs AND pre-permute edge_attr to CSR order as half
__global__ __launch_bounds__(256) void scatter_kernel(
    const int* __restrict__ ei, const float* __restrict__ edge_attr,
    int* __restrict__ cursor, int2* __restrict__ s_se,
    __half* __restrict__ s_ea) {
  int e = blockIdx.x * 256 + threadIdx.x;
  if (e >= NE) return;
  int src = ei[e], dst = ei[NE + e];
  int pos = atomicAdd(&cursor[dst], 1);
  s_se[pos] = make_int2(src, e);
  const float4* eap = (const float4*)(edge_attr + (size_t)e * 16);
  float4 a = eap[0], b = eap[1], c = eap[2], d = eap[3];
  uint4 u0, u1;
  __half2 h;
  h = __floats2half2_rn(a.x, a.y); u0.x = *(unsigned int*)&h;
  h = __floats2half2_rn(a.z, a.w); u0.y = *(unsigned int*)&h;
  h = __floats2half2_rn(b.x, b.y); u0.z = *(unsigned int*)&h;
  h = __floats2half2_rn(b.z, b.w); u0.w = *(unsigned int*)&h;
  h = __floats2half2_rn(c.x, c.y); u1.x = *(unsigned int*)&h;
  h = __floats2half2_rn(c.z, c.w); u1.y = *(unsigned int*)&h;
  h = __floats2half2_rn(d.x, d.y); u1.z = *(unsigned int*)&h;
  h = __floats2half2_rn(d.z, d.w); u1.w = *(unsigned int*)&h;
  uint4* outp = (uint4*)(s_ea + (size_t)pos * 16);
  outp[0] = u0; outp[1] = u1;
}

// ---------------- Kernel 3: aggregation + A/C epilogue -----------------
// one wave per dst node; 16 lanes per head; online softmax with defer-max.
// epilogue: out_n (mean over heads + skip) -> A[n]=out@W1[0:32], Cb[n]=out@W1[48:80]+b1
__global__ __launch_bounds__(256) void aggregate_kernel(
    const __half2* __restrict__ qh, const uint2* __restrict__ kvh,
    const float* __restrict__ qe, const __half* __restrict__ s_ea,
    const float* __restrict__ We,
    const float* __restrict__ x,
    const float* __restrict__ Wskip, const float* __restrict__ bskip,
    const float* __restrict__ W1, const float* __restrict__ b1,
    const int* __restrict__ offs, const int2* __restrict__ s_se,
    float* __restrict__ A, float* __restrict__ Cb) {
  int wave = threadIdx.x >> 6, lane = threadIdx.x & 63;
  int n = blockIdx.x * 4 + wave;
  if (n >= NN) return;
  int h = lane >> 4, t = lane & 15;
  int base = h * 32 + t;
  int gb = lane & 48;

  float2 qv = __half22float2(qh[n * 64 + lane]);
  float qet = qe[n * 64 + lane];
  int off = offs[n], end = offs[n + 1];

  float m = -INFINITY, s = 0.f, av0 = 0.f, av1 = 0.f, ae = 0.f;
  for (int j = off; j < end; j++) {
    int2 se = s_se[j];
    uint2 pk = kvh[(size_t)se.x * 64 + lane];
    float2 kf = __half22float2(*(const __half2*)&pk.x);
    float2 vf = __half22float2(*(const __half2*)&pk.y);
    float eat = __half2float(s_ea[(size_t)j * 16 + t]);
    float p = qv.x * kf.x + qv.y * kf.y + qet * eat;
    p += __shfl_xor(p, 1); p += __shfl_xor(p, 2);
    p += __shfl_xor(p, 4); p += __shfl_xor(p, 8);
    float alpha = p * 0.17677669529663687f;  // 1/sqrt(32)
    float d = alpha - m;
    if (d > 8.f) {  // defer-max: rescale only on large jumps (first edge included)
      float sc = __expf(-d);
      s *= sc; av0 *= sc; av1 *= sc; ae *= sc;
      m = alpha; d = 0.f;
    }
    float w = __expf(d);
    s += w;
    av0 += w * vf.x;
    av1 += w * vf.y;
    ae += w * eat;
  }
  float inv = (end > off) ? 1.f / s : 0.f;
  float r0 = av0 * inv, r1 = av1 * inv;
#pragma unroll
  for (int i = 0; i < 16; i++) {
    float aei = __shfl(ae, gb | i) * inv;
    r0 += aei * We[i * 128 + base];
    r1 += aei * We[i * 128 + base + 16];
  }
  // mean over heads (butterfly -> every lane holds the head-sum for its t)
  r0 += __shfl_xor(r0, 16); r0 += __shfl_xor(r0, 32);
  r1 += __shfl_xor(r1, 16); r1 += __shfl_xor(r1, 32);

  // skip connection computed in-place: skip_c = b + x@Wskip[:,c] for c=t, t+16
  float sk0 = bskip[t], sk1 = bskip[t + 16];
#pragma unroll
  for (int i = 0; i < 16; i++) {
    float xi = x[n * 16 + i];
    sk0 += xi * Wskip[i * 32 + t];
    sk1 += xi * Wskip[i * 32 + t + 16];
  }
  float o0 = 0.25f * r0 + sk0;  // out[n][t]
  float o1 = 0.25f * r1 + sk1;  // out[n][t+16]

  // A[n][j] = sum_i out_i*W1[i*32+j]; Cb[n][j] = sum_i out_i*W1[(48+i)*32+j] + b1[j]
  int j = lane & 31;
  int roff = (lane < 32) ? 0 : 48;
  float acc = (lane < 32) ? 0.f : b1[j];
#pragma unroll
  for (int i = 0; i < 16; i++) {
    float oi = __shfl(o0, i);
    acc += oi * W1[(roff + i) * 32 + j];
  }
#pragma unroll
  for (int i = 0; i < 16; i++) {
    float oi = __shfl(o1, i);
    acc += oi * W1[(roff + 16 + i) * 32 + j];
  }
  if (lane < 32) A[n * 32 + j] = acc;
  else           Cb[n * 32 + j] = acc;
}

// ---------------- Kernel 4: per-edge MLP, CSR order, wave per node -----
// 2 edges in flight per wave (two 32-lane groups); W1e/W2 columns in registers
__global__ __launch_bounds__(256) void mlp_kernel(
    const int2* __restrict__ s_se, const __half* __restrict__ s_ea,
    const int* __restrict__ offs,
    const float* __restrict__ A, const float* __restrict__ Cb,
    const float* __restrict__ W1, const float* __restrict__ W2,
    const float* __restrict__ b2v, float* __restrict__ out) {
  int wave = threadIdx.x >> 6, lane = threadIdx.x & 63;
  int n = blockIdx.x * 4 + wave;
  if (n >= NN) return;
  int g = lane >> 5, j = lane & 31;

  float w1e[16];
#pragma unroll
  for (int i = 0; i < 16; i++) w1e[i] = W1[(32 + i) * 32 + j];
  float w2j = W2[j];
  float cb = Cb[n * 32 + j];
  float b2s = b2v[0];
  int off = offs[n], end = offs[n + 1];

  for (int p = off + g; p < end; p += 2) {
    int2 se = s_se[p];
    float a = A[(size_t)se.x * 32 + j];
    const uint4* eap = (const uint4*)(s_ea + (size_t)p * 16);
    uint4 u0 = eap[0], u1 = eap[1];
    float hsum = a + cb;
    const __half2* hp0 = (const __half2*)&u0;
    const __half2* hp1 = (const __half2*)&u1;
#pragma unroll
    for (int i = 0; i < 4; i++) {
      float2 f0 = __half22float2(hp0[i]);
      hsum += f0.x * w1e[2 * i] + f0.y * w1e[2 * i + 1];
      float2 f1 = __half22float2(hp1[i]);
      hsum += f1.x * w1e[8 + 2 * i] + f1.y * w1e[8 + 2 * i + 1];
    }
    float hv = fmaxf(hsum, 0.f) * w2j;
    hv += __shfl_xor(hv, 1); hv += __shfl_xor(hv, 2);
    hv += __shfl_xor(hv, 4); hv += __shfl_xor(hv, 8);
    hv += __shfl_xor(hv, 16);
    if (j == 0) out[se.y] = hv + b2s;
  }
}

// ---------------- launch -----------------------------------------------
extern "C" void kernel_launch(void* const* d_in, const int* in_sizes, int n_in,
                              void* d_out, int out_size, void* d_ws, size_t ws_size,
                              hipStream_t stream) {
  const float* x         = (const float*)d_in[0];
  const int*   ei        = (const int*)d_in[1];
  const float* edge_attr = (const float*)d_in[2];
  const float* Wq = (const float*)d_in[3],  *bq = (const float*)d_in[4];
  const float* Wk = (const float*)d_in[5],  *bk = (const float*)d_in[6];
  const float* Wv = (const float*)d_in[7],  *bv = (const float*)d_in[8];
  const float* We = (const float*)d_in[9];
  const float* Wskip = (const float*)d_in[10], *bskip = (const float*)d_in[11];
  const float* W1 = (const float*)d_in[12], *b1 = (const float*)d_in[13];
  const float* W2 = (const float*)d_in[14], *b2 = (const float*)d_in[15];
  float* out = (float*)d_out;

  // workspace layout (all blocks are multiples of 32B)
  char* w = (char*)d_ws;
  uint2*   kvh  = (uint2*)w;            w += (size_t)NN * 64 * 8;   // 25.6 MB
  __half2* qh   = (__half2*)w;          w += (size_t)NN * 64 * 4;   // 12.8 MB
  float*   qe   = (float*)w;            w += (size_t)NN * 64 * 4;   // 12.8 MB
  float*   A    = (float*)w;            w += (size_t)NN * 32 * 4;   // 6.4 MB
  float*   Cb   = (float*)w;            w += (size_t)NN * 32 * 4;   // 6.4 MB
  __half*  s_ea = (__half*)w;           w += (size_t)NE * 16 * 2;   // 25.6 MB
  int2*    s_se = (int2*)w;             w += (size_t)NE * 8;        // 6.4 MB
  int*     counts = (int*)w;            w += (size_t)NN * 4;
  int*     offs   = (int*)w;            w += ((size_t)NN + 1) * 4;
  int*     cursor = (int*)w;            w += (size_t)NN * 4;

  hipMemsetAsync(counts, 0, NN * sizeof(int), stream);

  node_linear_kernel<<<NN / 4, 256, 0, stream>>>(x, Wq, bq, Wk, bk, Wv, bv, We,
                                                 qh, kvh, qe);
  count_kernel<<<NE / 256, 256, 0, stream>>>(ei, counts);
  scan_kernel<<<1, 1024, 0, stream>>>(counts, offs, cursor);
  scatter_kernel<<<NE / 256, 256, 0, stream>>>(ei, edge_attr, cursor, s_se, s_ea);
  aggregate_kernel<<<NN / 4, 256, 0, stream>>>(qh, kvh, qe, s_ea, We, x, Wskip,
                                               bskip, W1, b1, offs, s_se, A, Cb);
  mlp_kernel<<<NN / 4, 256, 0, stream>>>(s_se, s_ea, offs, A, Cb, W1, W2, b2, out);
}

// Round 3
// 468.306 us; speedup vs baseline: 1.0752x; 1.0520x over previous
//
#include <hip/hip_runtime.h>
#include <hip/hip_fp16.h>

#define NN 50000
#define NE 800000
// IN_C=16, EDGE_IN=16, HID=32, HEADS=4, HC=128
#define NODE_BLOCKS 12500   // NN/4
#define EDGE_BLOCKS 3125    // NE/256

// ---------------- Kernel 1: node linears + degree count (fused) --------
// blocks [0,NODE_BLOCKS): one wave per node.
// blocks [NODE_BLOCKS, NODE_BLOCKS+EDGE_BLOCKS): degree counting.
__global__ __launch_bounds__(256) void node_count_kernel(
    const float* __restrict__ x,
    const float* __restrict__ Wq, const float* __restrict__ bq,
    const float* __restrict__ Wk, const float* __restrict__ bk,
    const float* __restrict__ Wv, const float* __restrict__ bv,
    const float* __restrict__ We,
    const int* __restrict__ ei, int* __restrict__ counts,
    __half2* __restrict__ qh, uint2* __restrict__ kvh,
    float* __restrict__ qe) {
  if (blockIdx.x >= NODE_BLOCKS) {
    int e = (blockIdx.x - NODE_BLOCKS) * 256 + threadIdx.x;
    atomicAdd(&counts[ei[NE + e]], 1);
    return;
  }
  int wave = threadIdx.x >> 6;
  int lane = threadIdx.x & 63;
  int n = blockIdx.x * 4 + wave;
  int h = lane >> 4, t = lane & 15, base = h * 32 + t;

  float xr[16];
#pragma unroll
  for (int i = 0; i < 16; i++) xr[i] = x[n * 16 + i];

  float qb = bq[base], q16 = bq[base + 16];
  float kb = bk[base], k16 = bk[base + 16];
  float vb = bv[base], v16 = bv[base + 16];
#pragma unroll
  for (int i = 0; i < 16; i++) {
    qb  += xr[i] * Wq[i * 128 + base];
    q16 += xr[i] * Wq[i * 128 + base + 16];
    kb  += xr[i] * Wk[i * 128 + base];
    k16 += xr[i] * Wk[i * 128 + base + 16];
    vb  += xr[i] * Wv[i * 128 + base];
    v16 += xr[i] * Wv[i * 128 + base + 16];
  }
  qh[n * 64 + lane] = __floats2half2_rn(qb, q16);
  __half2 kk = __floats2half2_rn(kb, k16);
  __half2 vv = __floats2half2_rn(vb, v16);
  uint2 pk;
  pk.x = *(unsigned int*)&kk;
  pk.y = *(unsigned int*)&vv;
  kvh[n * 64 + lane] = pk;

  // qe[h][t] = sum_{c=0..31} q[h*32+c] * We[t*128 + h*32 + c]
  int gb = lane & 48;
  float acc = 0.f;
#pragma unroll
  for (int i = 0; i < 16; i++) {
    float qv  = __shfl(qb,  gb | i);
    float qv2 = __shfl(q16, gb | i);
    acc += qv * We[t * 128 + h * 32 + i] + qv2 * We[t * 128 + h * 32 + 16 + i];
  }
  qe[n * 64 + lane] = acc;
}

// ---------------- CSR build --------------------------------------------
__global__ __launch_bounds__(1024) void scan_kernel(const int* __restrict__ counts,
                                                    int* __restrict__ offs,
                                                    int* __restrict__ cursor) {
  __shared__ int sums[1024];
  int t = threadIdx.x;
  const int chunk = (NN + 1023) >> 10;
  int lo = t * chunk;
  int hi = lo + chunk; if (hi > NN) hi = NN;
  int sum = 0;
  for (int i = lo; i < hi; i++) sum += counts[i];
  sums[t] = sum;
  __syncthreads();
  for (int d = 1; d < 1024; d <<= 1) {
    int val = (t >= d) ? sums[t - d] : 0;
    __syncthreads();
    sums[t] += val;
    __syncthreads();
  }
  int run = (t == 0) ? 0 : sums[t - 1];
  for (int i = lo; i < hi; i++) {
    offs[i] = run; cursor[i] = run;
    run += counts[i];
  }
  if (t == 1023) offs[NN] = run;  // == NE
}

__global__ __launch_bounds__(256) void scatter_kernel(
    const int* __restrict__ ei, int* __restrict__ cursor,
    int2* __restrict__ s_se) {
  int e = blockIdx.x * 256 + threadIdx.x;
  if (e >= NE) return;
  int src = ei[e], dst = ei[NE + e];
  int pos = atomicAdd(&cursor[dst], 1);
  s_se[pos] = make_int2(src, e);
}

// ---------------- Kernel 3: aggregation + A/C epilogue -----------------
// one wave per dst node; 16 lanes per head; plain exp (no max subtraction:
// |alpha| is stochastically bounded ~12, fp32 exp safe to 88), 4-edge ILP.
__global__ __launch_bounds__(256) void aggregate_kernel(
    const __half2* __restrict__ qh, const uint2* __restrict__ kvh,
    const float* __restrict__ qe, const float* __restrict__ edge_attr,
    const float* __restrict__ We,
    const float* __restrict__ x,
    const float* __restrict__ Wskip, const float* __restrict__ bskip,
    const float* __restrict__ W1, const float* __restrict__ b1,
    const int* __restrict__ offs, const int2* __restrict__ s_se,
    float* __restrict__ A, float* __restrict__ Cb) {
  int wave = threadIdx.x >> 6, lane = threadIdx.x & 63;
  int n = blockIdx.x * 4 + wave;
  if (n >= NN) return;
  int h = lane >> 4, t = lane & 15;
  int base = h * 32 + t;
  int gb = lane & 48;
  const float SCALE = 0.17677669529663687f;  // 1/sqrt(32)

  float2 qv = __half22float2(qh[n * 64 + lane]);
  float qet = qe[n * 64 + lane];
  int off = offs[n], end = offs[n + 1];

  float s = 0.f, av0 = 0.f, av1 = 0.f, ae = 0.f;
  int j = off;
  for (; j + 4 <= end; j += 4) {
    const uint4* sp = (const uint4*)&s_se[j];
    uint4 sa = sp[0], sb = sp[1];
    int src0 = (int)sa.x, e0 = (int)sa.y;
    int src1 = (int)sa.z, e1 = (int)sa.w;
    int src2 = (int)sb.x, e2 = (int)sb.y;
    int src3 = (int)sb.z, e3 = (int)sb.w;
    uint2 pk0 = kvh[(size_t)src0 * 64 + lane];
    uint2 pk1 = kvh[(size_t)src1 * 64 + lane];
    uint2 pk2 = kvh[(size_t)src2 * 64 + lane];
    uint2 pk3 = kvh[(size_t)src3 * 64 + lane];
    float ea0 = edge_attr[(size_t)e0 * 16 + t];
    float ea1 = edge_attr[(size_t)e1 * 16 + t];
    float ea2 = edge_attr[(size_t)e2 * 16 + t];
    float ea3 = edge_attr[(size_t)e3 * 16 + t];
    float2 k0 = __half22float2(*(const __half2*)&pk0.x);
    float2 k1 = __half22float2(*(const __half2*)&pk1.x);
    float2 k2 = __half22float2(*(const __half2*)&pk2.x);
    float2 k3 = __half22float2(*(const __half2*)&pk3.x);
    float p0 = qv.x * k0.x + qv.y * k0.y + qet * ea0;
    float p1 = qv.x * k1.x + qv.y * k1.y + qet * ea1;
    float p2 = qv.x * k2.x + qv.y * k2.y + qet * ea2;
    float p3 = qv.x * k3.x + qv.y * k3.y + qet * ea3;
    p0 += __shfl_xor(p0, 1); p1 += __shfl_xor(p1, 1);
    p2 += __shfl_xor(p2, 1); p3 += __shfl_xor(p3, 1);
    p0 += __shfl_xor(p0, 2); p1 += __shfl_xor(p1, 2);
    p2 += __shfl_xor(p2, 2); p3 += __shfl_xor(p3, 2);
    p0 += __shfl_xor(p0, 4); p1 += __shfl_xor(p1, 4);
    p2 += __shfl_xor(p2, 4); p3 += __shfl_xor(p3, 4);
    p0 += __shfl_xor(p0, 8); p1 += __shfl_xor(p1, 8);
    p2 += __shfl_xor(p2, 8); p3 += __shfl_xor(p3, 8);
    float w0 = __expf(p0 * SCALE);
    float w1 = __expf(p1 * SCALE);
    float w2 = __expf(p2 * SCALE);
    float w3 = __expf(p3 * SCALE);
    float2 v0 = __half22float2(*(const __half2*)&pk0.y);
    float2 v1 = __half22float2(*(const __half2*)&pk1.y);
    float2 v2 = __half22float2(*(const __half2*)&pk2.y);
    float2 v3 = __half22float2(*(const __half2*)&pk3.y);
    s   += (w0 + w1) + (w2 + w3);
    av0 += (w0 * v0.x + w1 * v1.x) + (w2 * v2.x + w3 * v3.x);
    av1 += (w0 * v0.y + w1 * v1.y) + (w2 * v2.y + w3 * v3.y);
    ae  += (w0 * ea0 + w1 * ea1) + (w2 * ea2 + w3 * ea3);
  }
  for (; j < end; j++) {
    int2 se = s_se[j];
    uint2 pk = kvh[(size_t)se.x * 64 + lane];
    float2 kf = __half22float2(*(const __half2*)&pk.x);
    float2 vf = __half22float2(*(const __half2*)&pk.y);
    float eat = edge_attr[(size_t)se.y * 16 + t];
    float p = qv.x * kf.x + qv.y * kf.y + qet * eat;
    p += __shfl_xor(p, 1); p += __shfl_xor(p, 2);
    p += __shfl_xor(p, 4); p += __shfl_xor(p, 8);
    float w = __expf(p * SCALE);
    s += w;
    av0 += w * vf.x;
    av1 += w * vf.y;
    ae += w * eat;
  }
  float inv = (end > off) ? 1.f / s : 0.f;
  float r0 = av0 * inv, r1 = av1 * inv;
#pragma unroll
  for (int i = 0; i < 16; i++) {
    float aei = __shfl(ae, gb | i) * inv;
    r0 += aei * We[i * 128 + base];
    r1 += aei * We[i * 128 + base + 16];
  }
  // mean over heads
  r0 += __shfl_xor(r0, 16); r0 += __shfl_xor(r0, 32);
  r1 += __shfl_xor(r1, 16); r1 += __shfl_xor(r1, 32);

  // skip connection
  float sk0 = bskip[t], sk1 = bskip[t + 16];
#pragma unroll
  for (int i = 0; i < 16; i++) {
    float xi = x[n * 16 + i];
    sk0 += xi * Wskip[i * 32 + t];
    sk1 += xi * Wskip[i * 32 + t + 16];
  }
  float o0 = 0.25f * r0 + sk0;  // out[n][t]
  float o1 = 0.25f * r1 + sk1;  // out[n][t+16]

  // A[n][j] = out@W1[0:32]; Cb[n][j] = out@W1[48:80] + b1
  int jj = lane & 31;
  int roff = (lane < 32) ? 0 : 48;
  float acc = (lane < 32) ? 0.f : b1[jj];
#pragma unroll
  for (int i = 0; i < 16; i++) {
    float oi = __shfl(o0, i);
    acc += oi * W1[(roff + i) * 32 + jj];
  }
#pragma unroll
  for (int i = 0; i < 16; i++) {
    float oi = __shfl(o1, i);
    acc += oi * W1[(roff + 16 + i) * 32 + jj];
  }
  if (lane < 32) A[n * 32 + jj] = acc;
  else           Cb[n * 32 + jj] = acc;
}

// ---------------- Kernel 4: per-edge MLP, eid order --------------------
// one 32-lane group per edge, 8 edges per block
__global__ __launch_bounds__(256) void mlp_kernel(
    const int* __restrict__ ei, const float* __restrict__ edge_attr,
    const float* __restrict__ A, const float* __restrict__ Cb,
    const float* __restrict__ W1, const float* __restrict__ W2,
    const float* __restrict__ b2v, float* __restrict__ out) {
  int e = blockIdx.x * 8 + (threadIdx.x >> 5);
  int l = threadIdx.x & 31;
  int src = ei[e], dst = ei[NE + e];
  float hsum = A[(size_t)src * 32 + l] + Cb[(size_t)dst * 32 + l];
  float eav = edge_attr[(size_t)e * 16 + (l & 15)];  // lanes 16-31 replicate
#pragma unroll
  for (int i = 0; i < 16; i++) {
    float ev = __shfl(eav, i, 32);
    hsum += ev * W1[(32 + i) * 32 + l];
  }
  float hv = fmaxf(hsum, 0.f) * W2[l];
  hv += __shfl_xor(hv, 1); hv += __shfl_xor(hv, 2);
  hv += __shfl_xor(hv, 4); hv += __shfl_xor(hv, 8);
  hv += __shfl_xor(hv, 16);
  if (l == 0) out[e] = hv + b2v[0];
}

// ---------------- launch -----------------------------------------------
extern "C" void kernel_launch(void* const* d_in, const int* in_sizes, int n_in,
                              void* d_out, int out_size, void* d_ws, size_t ws_size,
                              hipStream_t stream) {
  const float* x         = (const float*)d_in[0];
  const int*   ei        = (const int*)d_in[1];
  const float* edge_attr = (const float*)d_in[2];
  const float* Wq = (const float*)d_in[3],  *bq = (const float*)d_in[4];
  const float* Wk = (const float*)d_in[5],  *bk = (const float*)d_in[6];
  const float* Wv = (const float*)d_in[7],  *bv = (const float*)d_in[8];
  const float* We = (const float*)d_in[9];
  const float* Wskip = (const float*)d_in[10], *bskip = (const float*)d_in[11];
  const float* W1 = (const float*)d_in[12], *b1 = (const float*)d_in[13];
  const float* W2 = (const float*)d_in[14], *b2 = (const float*)d_in[15];
  float* out = (float*)d_out;

  // workspace layout
  char* w = (char*)d_ws;
  uint2*   kvh  = (uint2*)w;            w += (size_t)NN * 64 * 8;   // 25.6 MB
  __half2* qh   = (__half2*)w;          w += (size_t)NN * 64 * 4;   // 12.8 MB
  float*   qe   = (float*)w;            w += (size_t)NN * 64 * 4;   // 12.8 MB
  float*   A    = (float*)w;            w += (size_t)NN * 32 * 4;   // 6.4 MB
  float*   Cb   = (float*)w;            w += (size_t)NN * 32 * 4;   // 6.4 MB
  int2*    s_se = (int2*)w;             w += (size_t)NE * 8;        // 6.4 MB
  int*     counts = (int*)w;            w += (size_t)NN * 4;
  int*     offs   = (int*)w;            w += ((size_t)NN + 1) * 4;
  int*     cursor = (int*)w;            w += (size_t)NN * 4;

  hipMemsetAsync(counts, 0, NN * sizeof(int), stream);

  node_count_kernel<<<NODE_BLOCKS + EDGE_BLOCKS, 256, 0, stream>>>(
      x, Wq, bq, Wk, bk, Wv, bv, We, ei, counts, qh, kvh, qe);
  scan_kernel<<<1, 1024, 0, stream>>>(counts, offs, cursor);
  scatter_kernel<<<EDGE_BLOCKS, 256, 0, stream>>>(ei, cursor, s_se);
  aggregate_kernel<<<NN / 4, 256, 0, stream>>>(qh, kvh, qe, edge_attr, We, x,
                                               Wskip, bskip, W1, b1, offs, s_se,
                                               A, Cb);
  mlp_kernel<<<NE / 8, 256, 0, stream>>>(ei, edge_attr, A, Cb, W1, W2, b2, out);
}

// Round 4
// 329.992 us; speedup vs baseline: 1.5259x; 1.4191x over previous
//
#include <hip/hip_runtime.h>
#include <hip/hip_fp16.h>

#define NN 50000
#define NE 800000
// IN_C=16, EDGE_IN=16, HID=32, HEADS=4, HC=128
#define NB 196            // coarse buckets = ceil(NN/256)
#define EPB 3125          // edges per bucket-build block (NE/256)

// ---------------- Kernel 1: node linears -------------------------------
// one wave per node; lane = (h=lane>>4, t=lane&15), base = h*32+t
__global__ __launch_bounds__(256) void node_linear_kernel(
    const float* __restrict__ x,
    const float* __restrict__ Wq, const float* __restrict__ bq,
    const float* __restrict__ Wk, const float* __restrict__ bk,
    const float* __restrict__ Wv, const float* __restrict__ bv,
    const float* __restrict__ We,
    __half2* __restrict__ qh, uint2* __restrict__ kvh,
    float* __restrict__ qe) {
  int wave = threadIdx.x >> 6;
  int lane = threadIdx.x & 63;
  int n = blockIdx.x * 4 + wave;
  if (n >= NN) return;
  int h = lane >> 4, t = lane & 15, base = h * 32 + t;

  float xr[16];
#pragma unroll
  for (int i = 0; i < 16; i++) xr[i] = x[n * 16 + i];

  float qb = bq[base], q16 = bq[base + 16];
  float kb = bk[base], k16 = bk[base + 16];
  float vb = bv[base], v16 = bv[base + 16];
#pragma unroll
  for (int i = 0; i < 16; i++) {
    qb  += xr[i] * Wq[i * 128 + base];
    q16 += xr[i] * Wq[i * 128 + base + 16];
    kb  += xr[i] * Wk[i * 128 + base];
    k16 += xr[i] * Wk[i * 128 + base + 16];
    vb  += xr[i] * Wv[i * 128 + base];
    v16 += xr[i] * Wv[i * 128 + base + 16];
  }
  qh[n * 64 + lane] = __floats2half2_rn(qb, q16);
  __half2 kk = __floats2half2_rn(kb, k16);
  __half2 vv = __floats2half2_rn(vb, v16);
  uint2 pk;
  pk.x = *(unsigned int*)&kk;
  pk.y = *(unsigned int*)&vv;
  kvh[n * 64 + lane] = pk;

  // qe[h][t] = sum_{c=0..31} q[h*32+c] * We[t*128 + h*32 + c]
  int gb = lane & 48;
  float acc = 0.f;
#pragma unroll
  for (int i = 0; i < 16; i++) {
    float qv  = __shfl(qb,  gb | i);
    float qv2 = __shfl(q16, gb | i);
    acc += qv * We[t * 128 + h * 32 + i] + qv2 * We[t * 128 + h * 32 + 16 + i];
  }
  qe[n * 64 + lane] = acc;
}

// ---------------- CSR build: bucketed counting sort, no global atomics --
// Pass 1: per-block LDS histogram over coarse buckets (dst>>8)
__global__ __launch_bounds__(256) void coarse_hist_kernel(
    const int* __restrict__ ei, int* __restrict__ hist_all) {
  __shared__ int hist[NB];
  int t = threadIdx.x, b = blockIdx.x;
  if (t < NB) hist[t] = 0;
  __syncthreads();
  int base = b * EPB;
  for (int i = t; i < EPB; i += 256)
    atomicAdd(&hist[ei[NE + base + i] >> 8], 1);
  __syncthreads();
  if (t < NB) hist_all[t * 256 + b] = hist[t];
}

// Pass 2 (1 block): per-bucket scan over blocks + scan of bucket totals.
// hist_all becomes global cursor for (bucket, block); coarse_offs[NB+1] set.
__global__ __launch_bounds__(256) void coarse_scan_kernel(
    int* __restrict__ hist_all, int* __restrict__ coarse_offs) {
  __shared__ int sc[256];
  int t = threadIdx.x;
  int run = 0;
  if (t < NB) {
    for (int i = 0; i < 256; i++) {
      int v = hist_all[t * 256 + i];
      hist_all[t * 256 + i] = run;   // exclusive within bucket
      run += v;
    }
  }
  sc[t] = (t < NB) ? run : 0;
  __syncthreads();
  for (int d = 1; d < 256; d <<= 1) {
    int v = (t >= d) ? sc[t - d] : 0;
    __syncthreads();
    sc[t] += v;
    __syncthreads();
  }
  int bbase = (t == 0) ? 0 : sc[t - 1];  // exclusive bucket base
  if (t <= NB) coarse_offs[t] = bbase;   // t==NB -> NE
  if (t < NB)
    for (int i = 0; i < 256; i++)
      hist_all[t * 256 + i] += bbase;
}

// Pass 3: scatter edges into coarse-bucket-grouped s_tmp via LDS cursors
__global__ __launch_bounds__(256) void bucket_scatter_kernel(
    const int* __restrict__ ei, const int* __restrict__ cursor_all,
    int2* __restrict__ s_tmp) {
  __shared__ int cur[NB];
  int t = threadIdx.x, b = blockIdx.x;
  if (t < NB) cur[t] = cursor_all[t * 256 + b];
  __syncthreads();
  int base = b * EPB;
  for (int i = t; i < EPB; i += 256) {
    int e = base + i;
    int src = ei[e], dst = ei[NE + e];
    int pos = atomicAdd(&cur[dst >> 8], 1);
    s_tmp[pos] = make_int2(src | ((dst & 255) << 16), e);
  }
}

// Pass 4: one block per bucket -> exact CSR (offs + s_se) via LDS count/scan
__global__ __launch_bounds__(256) void fine_csr_kernel(
    const int2* __restrict__ s_tmp, const int* __restrict__ coarse_offs,
    int2* __restrict__ s_se, int* __restrict__ offs) {
  __shared__ int cnt[256], sc[256], cur[256];
  int t = threadIdx.x, b = blockIdx.x;
  int lo = coarse_offs[b], hi = coarse_offs[b + 1];
  cnt[t] = 0;
  __syncthreads();
  for (int p = lo + t; p < hi; p += 256)
    atomicAdd(&cnt[(s_tmp[p].x >> 16) & 255], 1);
  __syncthreads();
  int myc = cnt[t];
  sc[t] = myc;
  __syncthreads();
  for (int d = 1; d < 256; d <<= 1) {
    int v = (t >= d) ? sc[t - d] : 0;
    __syncthreads();
    sc[t] += v;
    __syncthreads();
  }
  int excl = sc[t] - myc;
  cur[t] = lo + excl;
  int gd = b * 256 + t;
  if (gd <= NN) offs[gd] = lo + excl;  // gd==NN lands on b=195,t=80 -> NE
  __syncthreads();
  for (int p = lo + t; p < hi; p += 256) {
    int2 w = s_tmp[p];
    int pos = atomicAdd(&cur[(w.x >> 16) & 255], 1);
    s_se[pos] = make_int2(w.x & 0xFFFF, w.y);
  }
}

// ---------------- Kernel 3: aggregation + A/C epilogue -----------------
// one wave per dst node; 16 lanes per head; plain exp, 4-edge ILP.
__global__ __launch_bounds__(256) void aggregate_kernel(
    const __half2* __restrict__ qh, const uint2* __restrict__ kvh,
    const float* __restrict__ qe, const float* __restrict__ edge_attr,
    const float* __restrict__ We,
    const float* __restrict__ x,
    const float* __restrict__ Wskip, const float* __restrict__ bskip,
    const float* __restrict__ W1, const float* __restrict__ b1,
    const int* __restrict__ offs, const int2* __restrict__ s_se,
    float* __restrict__ A, float* __restrict__ Cb) {
  int wave = threadIdx.x >> 6, lane = threadIdx.x & 63;
  int n = blockIdx.x * 4 + wave;
  if (n >= NN) return;
  int h = lane >> 4, t = lane & 15;
  int base = h * 32 + t;
  int gb = lane & 48;
  const float SCALE = 0.17677669529663687f;  // 1/sqrt(32)

  float2 qv = __half22float2(qh[n * 64 + lane]);
  float qet = qe[n * 64 + lane];
  int off = offs[n], end = offs[n + 1];

  float s = 0.f, av0 = 0.f, av1 = 0.f, ae = 0.f;
  int j = off;
  for (; j + 4 <= end; j += 4) {
    const uint4* sp = (const uint4*)&s_se[j];
    uint4 sa = sp[0], sb = sp[1];
    int src0 = (int)sa.x, e0 = (int)sa.y;
    int src1 = (int)sa.z, e1 = (int)sa.w;
    int src2 = (int)sb.x, e2 = (int)sb.y;
    int src3 = (int)sb.z, e3 = (int)sb.w;
    uint2 pk0 = kvh[(size_t)src0 * 64 + lane];
    uint2 pk1 = kvh[(size_t)src1 * 64 + lane];
    uint2 pk2 = kvh[(size_t)src2 * 64 + lane];
    uint2 pk3 = kvh[(size_t)src3 * 64 + lane];
    float ea0 = edge_attr[(size_t)e0 * 16 + t];
    float ea1 = edge_attr[(size_t)e1 * 16 + t];
    float ea2 = edge_attr[(size_t)e2 * 16 + t];
    float ea3 = edge_attr[(size_t)e3 * 16 + t];
    float2 k0 = __half22float2(*(const __half2*)&pk0.x);
    float2 k1 = __half22float2(*(const __half2*)&pk1.x);
    float2 k2 = __half22float2(*(const __half2*)&pk2.x);
    float2 k3 = __half22float2(*(const __half2*)&pk3.x);
    float p0 = qv.x * k0.x + qv.y * k0.y + qet * ea0;
    float p1 = qv.x * k1.x + qv.y * k1.y + qet * ea1;
    float p2 = qv.x * k2.x + qv.y * k2.y + qet * ea2;
    float p3 = qv.x * k3.x + qv.y * k3.y + qet * ea3;
    p0 += __shfl_xor(p0, 1); p1 += __shfl_xor(p1, 1);
    p2 += __shfl_xor(p2, 1); p3 += __shfl_xor(p3, 1);
    p0 += __shfl_xor(p0, 2); p1 += __shfl_xor(p1, 2);
    p2 += __shfl_xor(p2, 2); p3 += __shfl_xor(p3, 2);
    p0 += __shfl_xor(p0, 4); p1 += __shfl_xor(p1, 4);
    p2 += __shfl_xor(p2, 4); p3 += __shfl_xor(p3, 4);
    p0 += __shfl_xor(p0, 8); p1 += __shfl_xor(p1, 8);
    p2 += __shfl_xor(p2, 8); p3 += __shfl_xor(p3, 8);
    float w0 = __expf(p0 * SCALE);
    float w1 = __expf(p1 * SCALE);
    float w2 = __expf(p2 * SCALE);
    float w3 = __expf(p3 * SCALE);
    float2 v0 = __half22float2(*(const __half2*)&pk0.y);
    float2 v1 = __half22float2(*(const __half2*)&pk1.y);
    float2 v2 = __half22float2(*(const __half2*)&pk2.y);
    float2 v3 = __half22float2(*(const __half2*)&pk3.y);
    s   += (w0 + w1) + (w2 + w3);
    av0 += (w0 * v0.x + w1 * v1.x) + (w2 * v2.x + w3 * v3.x);
    av1 += (w0 * v0.y + w1 * v1.y) + (w2 * v2.y + w3 * v3.y);
    ae  += (w0 * ea0 + w1 * ea1) + (w2 * ea2 + w3 * ea3);
  }
  for (; j < end; j++) {
    int2 se = s_se[j];
    uint2 pk = kvh[(size_t)se.x * 64 + lane];
    float2 kf = __half22float2(*(const __half2*)&pk.x);
    float2 vf = __half22float2(*(const __half2*)&pk.y);
    float eat = edge_attr[(size_t)se.y * 16 + t];
    float p = qv.x * kf.x + qv.y * kf.y + qet * eat;
    p += __shfl_xor(p, 1); p += __shfl_xor(p, 2);
    p += __shfl_xor(p, 4); p += __shfl_xor(p, 8);
    float w = __expf(p * SCALE);
    s += w;
    av0 += w * vf.x;
    av1 += w * vf.y;
    ae += w * eat;
  }
  float inv = (end > off) ? 1.f / s : 0.f;
  float r0 = av0 * inv, r1 = av1 * inv;
#pragma unroll
  for (int i = 0; i < 16; i++) {
    float aei = __shfl(ae, gb | i) * inv;
    r0 += aei * We[i * 128 + base];
    r1 += aei * We[i * 128 + base + 16];
  }
  // mean over heads
  r0 += __shfl_xor(r0, 16); r0 += __shfl_xor(r0, 32);
  r1 += __shfl_xor(r1, 16); r1 += __shfl_xor(r1, 32);

  // skip connection
  float sk0 = bskip[t], sk1 = bskip[t + 16];
#pragma unroll
  for (int i = 0; i < 16; i++) {
    float xi = x[n * 16 + i];
    sk0 += xi * Wskip[i * 32 + t];
    sk1 += xi * Wskip[i * 32 + t + 16];
  }
  float o0 = 0.25f * r0 + sk0;  // out[n][t]
  float o1 = 0.25f * r1 + sk1;  // out[n][t+16]

  // A[n][j] = out@W1[0:32]; Cb[n][j] = out@W1[48:80] + b1
  int jj = lane & 31;
  int roff = (lane < 32) ? 0 : 48;
  float acc = (lane < 32) ? 0.f : b1[jj];
#pragma unroll
  for (int i = 0; i < 16; i++) {
    float oi = __shfl(o0, i);
    acc += oi * W1[(roff + i) * 32 + jj];
  }
#pragma unroll
  for (int i = 0; i < 16; i++) {
    float oi = __shfl(o1, i);
    acc += oi * W1[(roff + 16 + i) * 32 + jj];
  }
  if (lane < 32) A[n * 32 + jj] = acc;
  else           Cb[n * 32 + jj] = acc;
}

// ---------------- Kernel 4: per-edge MLP, eid order --------------------
// one 32-lane group per edge, 8 edges per block
__global__ __launch_bounds__(256) void mlp_kernel(
    const int* __restrict__ ei, const float* __restrict__ edge_attr,
    const float* __restrict__ A, const float* __restrict__ Cb,
    const float* __restrict__ W1, const float* __restrict__ W2,
    const float* __restrict__ b2v, float* __restrict__ out) {
  int e = blockIdx.x * 8 + (threadIdx.x >> 5);
  int l = threadIdx.x & 31;
  int src = ei[e], dst = ei[NE + e];
  float hsum = A[(size_t)src * 32 + l] + Cb[(size_t)dst * 32 + l];
  float eav = edge_attr[(size_t)e * 16 + (l & 15)];  // lanes 16-31 replicate
#pragma unroll
  for (int i = 0; i < 16; i++) {
    float ev = __shfl(eav, i, 32);
    hsum += ev * W1[(32 + i) * 32 + l];
  }
  float hv = fmaxf(hsum, 0.f) * W2[l];
  hv += __shfl_xor(hv, 1); hv += __shfl_xor(hv, 2);
  hv += __shfl_xor(hv, 4); hv += __shfl_xor(hv, 8);
  hv += __shfl_xor(hv, 16);
  if (l == 0) out[e] = hv + b2v[0];
}

// ---------------- launch -----------------------------------------------
extern "C" void kernel_launch(void* const* d_in, const int* in_sizes, int n_in,
                              void* d_out, int out_size, void* d_ws, size_t ws_size,
                              hipStream_t stream) {
  const float* x         = (const float*)d_in[0];
  const int*   ei        = (const int*)d_in[1];
  const float* edge_attr = (const float*)d_in[2];
  const float* Wq = (const float*)d_in[3],  *bq = (const float*)d_in[4];
  const float* Wk = (const float*)d_in[5],  *bk = (const float*)d_in[6];
  const float* Wv = (const float*)d_in[7],  *bv = (const float*)d_in[8];
  const float* We = (const float*)d_in[9];
  const float* Wskip = (const float*)d_in[10], *bskip = (const float*)d_in[11];
  const float* W1 = (const float*)d_in[12], *b1 = (const float*)d_in[13];
  const float* W2 = (const float*)d_in[14], *b2 = (const float*)d_in[15];
  float* out = (float*)d_out;

  // workspace layout
  char* w = (char*)d_ws;
  uint2*   kvh  = (uint2*)w;            w += (size_t)NN * 64 * 8;   // 25.6 MB
  __half2* qh   = (__half2*)w;          w += (size_t)NN * 64 * 4;   // 12.8 MB
  float*   qe   = (float*)w;            w += (size_t)NN * 64 * 4;   // 12.8 MB
  float*   A    = (float*)w;            w += (size_t)NN * 32 * 4;   // 6.4 MB
  float*   Cb   = (float*)w;            w += (size_t)NN * 32 * 4;   // 6.4 MB
  int2*    s_se = (int2*)w;             w += (size_t)NE * 8;        // 6.4 MB
  int2*    s_tmp = (int2*)w;            w += (size_t)NE * 8;        // 6.4 MB
  int*     hist_all = (int*)w;          w += (size_t)256 * 256 * 4; // 256 KB
  int*     coarse_offs = (int*)w;       w += 256 * 4;
  int*     offs = (int*)w;              w += ((size_t)NN + 1) * 4;

  node_linear_kernel<<<NN / 4, 256, 0, stream>>>(x, Wq, bq, Wk, bk, Wv, bv, We,
                                                 qh, kvh, qe);
  coarse_hist_kernel<<<256, 256, 0, stream>>>(ei, hist_all);
  coarse_scan_kernel<<<1, 256, 0, stream>>>(hist_all, coarse_offs);
  bucket_scatter_kernel<<<256, 256, 0, stream>>>(ei, hist_all, s_tmp);
  fine_csr_kernel<<<NB, 256, 0, stream>>>(s_tmp, coarse_offs, s_se, offs);
  aggregate_kernel<<<NN / 4, 256, 0, stream>>>(qh, kvh, qe, edge_attr, We, x,
                                               Wskip, bskip, W1, b1, offs, s_se,
                                               A, Cb);
  mlp_kernel<<<NE / 8, 256, 0, stream>>>(ei, edge_attr, A, Cb, W1, W2, b2, out);
}

// Round 5
// 311.789 us; speedup vs baseline: 1.6150x; 1.0584x over previous
//
#include <hip/hip_runtime.h>
#include <hip/hip_fp16.h>

#define NN 50000
#define NE 800000
// IN_C=16, EDGE_IN=16, HID=32, HEADS=4, HC=128
#define NB 196            // coarse buckets = ceil(NN/256)
#define EPB 3125          // edges per bucket-build block (NE/256)
#define NODE_BLOCKS 12500 // NN/4

// scale folded into q/qe at production time: 1/sqrt(32) * log2(e)
#define QSCALE 0.25506413f

typedef _Float16 half2v __attribute__((ext_vector_type(2)));

static __device__ __forceinline__ float fdot2h(unsigned a, unsigned b, float c) {
#if __has_builtin(__builtin_amdgcn_fdot2)
  return __builtin_amdgcn_fdot2(__builtin_bit_cast(half2v, a),
                                __builtin_bit_cast(half2v, b), c, false);
#else
  float2 fa = __half22float2(*(const __half2*)&a);
  float2 fb = __half22float2(*(const __half2*)&b);
  return fa.x * fb.x + fa.y * fb.y + c;
#endif
}

// ---------------- Kernel 1: node linears + coarse hist (fused) ---------
__global__ __launch_bounds__(256) void node_linear_kernel(
    const float* __restrict__ x,
    const float* __restrict__ Wq, const float* __restrict__ bq,
    const float* __restrict__ Wk, const float* __restrict__ bk,
    const float* __restrict__ Wv, const float* __restrict__ bv,
    const float* __restrict__ We,
    const int* __restrict__ ei, int* __restrict__ hist_all,
    __half2* __restrict__ qh, uint2* __restrict__ kvh,
    float* __restrict__ qe) {
  __shared__ int hist[NB];
  if (blockIdx.x >= NODE_BLOCKS) {
    int b = blockIdx.x - NODE_BLOCKS;  // [0,256)
    int t = threadIdx.x;
    if (t < NB) hist[t] = 0;
    __syncthreads();
    int base = b * EPB;
    for (int i = t; i < EPB; i += 256)
      atomicAdd(&hist[ei[NE + base + i] >> 8], 1);
    __syncthreads();
    if (t < NB) hist_all[t * 256 + b] = hist[t];
    return;
  }
  int wave = threadIdx.x >> 6;
  int lane = threadIdx.x & 63;
  int n = blockIdx.x * 4 + wave;
  int h = lane >> 4, t = lane & 15, base = h * 32 + t;

  float xr[16];
#pragma unroll
  for (int i = 0; i < 16; i++) xr[i] = x[n * 16 + i];

  float qb = bq[base], q16 = bq[base + 16];
  float kb = bk[base], k16 = bk[base + 16];
  float vb = bv[base], v16 = bv[base + 16];
#pragma unroll
  for (int i = 0; i < 16; i++) {
    qb  += xr[i] * Wq[i * 128 + base];
    q16 += xr[i] * Wq[i * 128 + base + 16];
    kb  += xr[i] * Wk[i * 128 + base];
    k16 += xr[i] * Wk[i * 128 + base + 16];
    vb  += xr[i] * Wv[i * 128 + base];
    v16 += xr[i] * Wv[i * 128 + base + 16];
  }
  qh[n * 64 + lane] = __floats2half2_rn(qb * QSCALE, q16 * QSCALE);
  __half2 kk = __floats2half2_rn(kb, k16);
  __half2 vv = __floats2half2_rn(vb, v16);
  uint2 pk;
  pk.x = *(unsigned int*)&kk;
  pk.y = *(unsigned int*)&vv;
  kvh[n * 64 + lane] = pk;

  // qe[h][t] = sum_c q[h*32+c] * We[t*128 + h*32 + c]   (scaled by QSCALE)
  int gb = lane & 48;
  float acc = 0.f;
#pragma unroll
  for (int i = 0; i < 16; i++) {
    float qv  = __shfl(qb,  gb | i);
    float qv2 = __shfl(q16, gb | i);
    acc += qv * We[t * 128 + h * 32 + i] + qv2 * We[t * 128 + h * 32 + 16 + i];
  }
  qe[n * 64 + lane] = acc * QSCALE;
}

// ---------------- CSR build ---------------------------------------------
// one wave per bucket: parallel scan of its 256 block-entries (in-place excl)
__global__ __launch_bounds__(256) void scan_buckets_kernel(
    int* __restrict__ hist_all, int* __restrict__ btot) {
  int wv = blockIdx.x * 4 + (threadIdx.x >> 6);
  int l = threadIdx.x & 63;
  if (wv >= NB) return;
  int base = wv * 256;
  int run = 0;
#pragma unroll
  for (int c = 0; c < 4; c++) {
    int v = hist_all[base + c * 64 + l];
    int orig = v;
#pragma unroll
    for (int d = 1; d < 64; d <<= 1) {
      int u = __shfl_up(v, d);
      if (l >= d) v += u;
    }
    hist_all[base + c * 64 + l] = run + v - orig;
    run += __shfl(v, 63);
  }
  if (l == 0) btot[wv] = run;
}

__global__ __launch_bounds__(256) void tiny_scan_kernel(
    const int* __restrict__ btot, int* __restrict__ coarse_offs) {
  __shared__ int sc[256];
  int t = threadIdx.x;
  int v = (t < NB) ? btot[t] : 0;
  sc[t] = v;
  __syncthreads();
  for (int d = 1; d < 256; d <<= 1) {
    int u = (t >= d) ? sc[t - d] : 0;
    __syncthreads();
    sc[t] += u;
    __syncthreads();
  }
  if (t < NB) coarse_offs[t] = sc[t] - v;
  if (t == NB - 1) coarse_offs[NB] = sc[t];
}

// scatter edges into coarse-bucket-grouped s_tmp via LDS cursors
__global__ __launch_bounds__(256) void bucket_scatter_kernel(
    const int* __restrict__ ei, const int* __restrict__ cursor_all,
    const int* __restrict__ coarse_offs, int2* __restrict__ s_tmp) {
  __shared__ int cur[NB];
  int t = threadIdx.x, b = blockIdx.x;
  if (t < NB) cur[t] = cursor_all[t * 256 + b] + coarse_offs[t];
  __syncthreads();
  int base = b * EPB;
  for (int i = t; i < EPB; i += 256) {
    int e = base + i;
    int src = ei[e], dst = ei[NE + e];
    int pos = atomicAdd(&cur[dst >> 8], 1);
    s_tmp[pos] = make_int2(src | ((dst & 255) << 16), e);
  }
}

// one block per bucket -> exact CSR (offs + s_se) via LDS count/scan
__global__ __launch_bounds__(256) void fine_csr_kernel(
    const int2* __restrict__ s_tmp, const int* __restrict__ coarse_offs,
    int2* __restrict__ s_se, int* __restrict__ offs) {
  __shared__ int cnt[256], sc[256], cur[256];
  int t = threadIdx.x, b = blockIdx.x;
  int lo = coarse_offs[b], hi = coarse_offs[b + 1];
  cnt[t] = 0;
  __syncthreads();
  for (int p = lo + t; p < hi; p += 256)
    atomicAdd(&cnt[(s_tmp[p].x >> 16) & 255], 1);
  __syncthreads();
  int myc = cnt[t];
  sc[t] = myc;
  __syncthreads();
  for (int d = 1; d < 256; d <<= 1) {
    int v = (t >= d) ? sc[t - d] : 0;
    __syncthreads();
    sc[t] += v;
    __syncthreads();
  }
  int excl = sc[t] - myc;
  cur[t] = lo + excl;
  int gd = b * 256 + t;
  if (gd <= NN) offs[gd] = lo + excl;
  __syncthreads();
  for (int p = lo + t; p < hi; p += 256) {
    int2 w = s_tmp[p];
    int pos = atomicAdd(&cur[(w.x >> 16) & 255], 1);
    s_se[pos] = make_int2(w.x & 0xFFFF, w.y);
  }
}

// ---------------- Kernel 3: aggregation + A/C epilogue -----------------
// one wave per dst node; 16 lanes/head; plain exp2 (q,qe pre-scaled), 8-edge ILP
__global__ __launch_bounds__(256) void aggregate_kernel(
    const __half2* __restrict__ qh, const uint2* __restrict__ kvh,
    const float* __restrict__ qe, const float* __restrict__ edge_attr,
    const float* __restrict__ We,
    const float* __restrict__ x,
    const float* __restrict__ Wskip, const float* __restrict__ bskip,
    const float* __restrict__ W1, const float* __restrict__ b1,
    const int* __restrict__ offs, const int2* __restrict__ s_se,
    float* __restrict__ A, float* __restrict__ Cb) {
  int wave = threadIdx.x >> 6, lane = threadIdx.x & 63;
  int n = blockIdx.x * 4 + wave;
  if (n >= NN) return;
  int h = lane >> 4, t = lane & 15;
  int base = h * 32 + t;
  int gb = lane & 48;

  unsigned q2 = *(const unsigned*)&qh[n * 64 + lane];
  float qet = qe[n * 64 + lane];
  int off = offs[n], end = offs[n + 1];

  float s = 0.f, av0 = 0.f, av1 = 0.f, ae = 0.f;
  int j = off;
  for (; j + 8 <= end; j += 8) {
    const uint4* sp = (const uint4*)&s_se[j];
    uint4 sa[4];
#pragma unroll
    for (int u = 0; u < 4; u++) sa[u] = sp[u];
    uint2 pk[8];
    float ea[8];
#pragma unroll
    for (int u = 0; u < 8; u++) {
      unsigned srcu = (u & 1) ? sa[u >> 1].z : sa[u >> 1].x;
      unsigned eu   = (u & 1) ? sa[u >> 1].w : sa[u >> 1].y;
      pk[u] = kvh[srcu * 64u + (unsigned)lane];
      ea[u] = edge_attr[eu * 16u + (unsigned)t];
    }
    float p[8];
#pragma unroll
    for (int u = 0; u < 8; u++) p[u] = fdot2h(q2, pk[u].x, qet * ea[u]);
#pragma unroll
    for (int d = 1; d < 16; d <<= 1) {
#pragma unroll
      for (int u = 0; u < 8; u++) p[u] += __shfl_xor(p[u], d);
    }
#pragma unroll
    for (int u = 0; u < 8; u++) {
      float w = exp2f(p[u]);
      float2 vf = __half22float2(*(const __half2*)&pk[u].y);
      s   += w;
      av0 += w * vf.x;
      av1 += w * vf.y;
      ae  += w * ea[u];
    }
  }
  for (; j < end; j++) {
    int2 se = s_se[j];
    uint2 pk = kvh[(unsigned)se.x * 64u + (unsigned)lane];
    float eat = edge_attr[(unsigned)se.y * 16u + (unsigned)t];
    float p = fdot2h(q2, pk.x, qet * eat);
    p += __shfl_xor(p, 1); p += __shfl_xor(p, 2);
    p += __shfl_xor(p, 4); p += __shfl_xor(p, 8);
    float w = exp2f(p);
    float2 vf = __half22float2(*(const __half2*)&pk.y);
    s += w;
    av0 += w * vf.x;
    av1 += w * vf.y;
    ae += w * eat;
  }
  float inv = (end > off) ? 1.f / s : 0.f;
  float r0 = av0 * inv, r1 = av1 * inv;
#pragma unroll
  for (int i = 0; i < 16; i++) {
    float aei = __shfl(ae, gb | i) * inv;
    r0 += aei * We[i * 128 + base];
    r1 += aei * We[i * 128 + base + 16];
  }
  // mean over heads
  r0 += __shfl_xor(r0, 16); r0 += __shfl_xor(r0, 32);
  r1 += __shfl_xor(r1, 16); r1 += __shfl_xor(r1, 32);

  // skip connection
  float sk0 = bskip[t], sk1 = bskip[t + 16];
#pragma unroll
  for (int i = 0; i < 16; i++) {
    float xi = x[n * 16 + i];
    sk0 += xi * Wskip[i * 32 + t];
    sk1 += xi * Wskip[i * 32 + t + 16];
  }
  float o0 = 0.25f * r0 + sk0;  // out[n][t]
  float o1 = 0.25f * r1 + sk1;  // out[n][t+16]

  // A[n][j] = out@W1[0:32]; Cb[n][j] = out@W1[48:80] + b1
  int jj = lane & 31;
  int roff = (lane < 32) ? 0 : 48;
  float acc = (lane < 32) ? 0.f : b1[jj];
#pragma unroll
  for (int i = 0; i < 16; i++) {
    float oi = __shfl(o0, i);
    acc += oi * W1[(roff + i) * 32 + jj];
  }
#pragma unroll
  for (int i = 0; i < 16; i++) {
    float oi = __shfl(o1, i);
    acc += oi * W1[(roff + 16 + i) * 32 + jj];
  }
  if (lane < 32) A[n * 32 + jj] = acc;
  else           Cb[n * 32 + jj] = acc;
}

// ---------------- Kernel 4: per-edge MLP, eid order --------------------
__global__ __launch_bounds__(256) void mlp_kernel(
    const int* __restrict__ ei, const float* __restrict__ edge_attr,
    const float* __restrict__ A, const float* __restrict__ Cb,
    const float* __restrict__ W1, const float* __restrict__ W2,
    const float* __restrict__ b2v, float* __restrict__ out) {
  int e = blockIdx.x * 8 + (threadIdx.x >> 5);
  int l = threadIdx.x & 31;
  unsigned src = (unsigned)ei[e], dst = (unsigned)ei[NE + e];
  float hsum = A[src * 32u + l] + Cb[dst * 32u + l];
  float eav = edge_attr[(unsigned)e * 16u + (l & 15)];
#pragma unroll
  for (int i = 0; i < 16; i++) {
    float ev = __shfl(eav, i, 32);
    hsum += ev * W1[(32 + i) * 32 + l];
  }
  float hv = fmaxf(hsum, 0.f) * W2[l];
  hv += __shfl_xor(hv, 1); hv += __shfl_xor(hv, 2);
  hv += __shfl_xor(hv, 4); hv += __shfl_xor(hv, 8);
  hv += __shfl_xor(hv, 16);
  if (l == 0) out[e] = hv + b2v[0];
}

// ---------------- launch -----------------------------------------------
extern "C" void kernel_launch(void* const* d_in, const int* in_sizes, int n_in,
                              void* d_out, int out_size, void* d_ws, size_t ws_size,
                              hipStream_t stream) {
  const float* x         = (const float*)d_in[0];
  const int*   ei        = (const int*)d_in[1];
  const float* edge_attr = (const float*)d_in[2];
  const float* Wq = (const float*)d_in[3],  *bq = (const float*)d_in[4];
  const float* Wk = (const float*)d_in[5],  *bk = (const float*)d_in[6];
  const float* Wv = (const float*)d_in[7],  *bv = (const float*)d_in[8];
  const float* We = (const float*)d_in[9];
  const float* Wskip = (const float*)d_in[10], *bskip = (const float*)d_in[11];
  const float* W1 = (const float*)d_in[12], *b1 = (const float*)d_in[13];
  const float* W2 = (const float*)d_in[14], *b2 = (const float*)d_in[15];
  float* out = (float*)d_out;

  // workspace layout
  char* w = (char*)d_ws;
  uint2*   kvh  = (uint2*)w;            w += (size_t)NN * 64 * 8;   // 25.6 MB
  __half2* qh   = (__half2*)w;          w += (size_t)NN * 64 * 4;   // 12.8 MB
  float*   qe   = (float*)w;            w += (size_t)NN * 64 * 4;   // 12.8 MB
  float*   A    = (float*)w;            w += (size_t)NN * 32 * 4;   // 6.4 MB
  float*   Cb   = (float*)w;            w += (size_t)NN * 32 * 4;   // 6.4 MB
  int2*    s_se = (int2*)w;             w += (size_t)NE * 8;        // 6.4 MB
  int2*    s_tmp = (int2*)w;            w += (size_t)NE * 8;        // 6.4 MB
  int*     hist_all = (int*)w;          w += (size_t)256 * 256 * 4; // 256 KB
  int*     btot = (int*)w;              w += 256 * 4;
  int*     coarse_offs = (int*)w;       w += 256 * 4;
  int*     offs = (int*)w;              w += ((size_t)NN + 1) * 4;

  node_linear_kernel<<<NODE_BLOCKS + 256, 256, 0, stream>>>(
      x, Wq, bq, Wk, bk, Wv, bv, We, ei, hist_all, qh, kvh, qe);
  scan_buckets_kernel<<<49, 256, 0, stream>>>(hist_all, btot);
  tiny_scan_kernel<<<1, 256, 0, stream>>>(btot, coarse_offs);
  bucket_scatter_kernel<<<256, 256, 0, stream>>>(ei, hist_all, coarse_offs, s_tmp);
  fine_csr_kernel<<<NB, 256, 0, stream>>>(s_tmp, coarse_offs, s_se, offs);
  aggregate_kernel<<<NN / 4, 256, 0, stream>>>(qh, kvh, qe, edge_attr, We, x,
                                               Wskip, bskip, W1, b1, offs, s_se,
                                               A, Cb);
  mlp_kernel<<<NE / 8, 256, 0, stream>>>(ei, edge_attr, A, Cb, W1, W2, b2, out);
}